// Round 1
// baseline (42.494 us; speedup 1.0000x reference)
//
#include <hip/hip_runtime.h>

// YOLO loss: S=7, B=2, C=20, LAMBDA_COORD=5, LAMBDA_NOOBJ=0.5, N=8192.
// pred:   (8192, 49*30) f32   target: (8192, 49*25) f32   out: scalar f32.
// One thread per grid cell (M = 8192*49). Pure streaming reduction.

#define NBATCH 8192
#define CELLS  49          // S*S
#define PSTRIDE 30         // 5*B + C
#define TSTRIDE 25         // 5 + C

__global__ __launch_bounds__(256) void yolo_loss_kernel(
    const float* __restrict__ pred,
    const float* __restrict__ tgt,
    float* __restrict__ out,
    int M, float invN)
{
    int i = blockIdx.x * blockDim.x + threadIdx.x;
    float part = 0.0f;

    if (i < M) {
        const float* p = pred + (size_t)i * PSTRIDE;
        const float* t = tgt  + (size_t)i * TSTRIDE;

        int cell = i % CELLS;
        float gy = (float)(cell / 7);
        float gx = (float)(cell % 7);
        const float invS = 1.0f / 7.0f;

        float t0 = t[0], tx = t[1], ty = t[2], tw = t[3], th = t[4];
        float objf   = (t0 == 1.0f) ? 1.0f : 0.0f;
        float noobjf = (t0 == 0.0f) ? 1.0f : 0.0f;

        // target box -> xyxy
        float tcx = (gx + tx) * invS, tcy = (gy + ty) * invS;
        float tx1 = tcx - tw * 0.5f, ty1 = tcy - th * 0.5f;
        float tx2 = tcx + tw * 0.5f, ty2 = tcy + th * 0.5f;
        float area_t = (tx2 - tx1) * (ty2 - ty1);

        float conf[2], bx[2], by[2], bw[2], bh[2], iou[2];
        #pragma unroll
        for (int b = 0; b < 2; ++b) {
            conf[b] = p[b * 5 + 0];
            bx[b]   = p[b * 5 + 1];
            by[b]   = p[b * 5 + 2];
            bw[b]   = p[b * 5 + 3];
            bh[b]   = p[b * 5 + 4];
            float ax = fabsf(bx[b]), ay = fabsf(by[b]);
            float aw = fabsf(bw[b]), ah = fabsf(bh[b]);
            float cx = (gx + ax) * invS, cy = (gy + ay) * invS;
            float x1 = cx - aw * 0.5f, y1 = cy - ah * 0.5f;
            float x2 = cx + aw * 0.5f, y2 = cy + ah * 0.5f;
            float ltx = fmaxf(x1, tx1), lty = fmaxf(y1, ty1);
            float rbx = fminf(x2, tx2), rby = fminf(y2, ty2);
            float wx = fmaxf(rbx - ltx, 0.0f);
            float wy = fmaxf(rby - lty, 0.0f);
            float inter = wx * wy;
            float area_p = (x2 - x1) * (y2 - y1);
            iou[b] = inter / (area_p + area_t - inter);
        }

        // argmax (first index wins ties -> strict > for box 1)
        int best = (iou[1] > iou[0]) ? 1 : 0;
        float miou = fmaxf(iou[0], iou[1]);

        float rc = conf[best];
        float rx = bx[best], ry = by[best], rw = bw[best], rh = bh[best];

        // localization (xy on raw resp, wh on sqrt(abs))
        float dx = rx - tx, dy = ry - ty;
        float sw = sqrtf(fabsf(rw)) - sqrtf(fabsf(tw));
        float sh = sqrtf(fabsf(rh)) - sqrtf(fabsf(th));
        float loc = dx * dx + dy * dy + sw * sw + sh * sh;

        float oc = rc - miou;
        oc = oc * oc;

        float no = conf[0] * conf[0] + conf[1] * conf[1];

        float cls = 0.0f;
        #pragma unroll
        for (int k = 0; k < 20; ++k) {
            float d = p[10 + k] - t[5 + k];
            cls += d * d;
        }

        part = objf * (5.0f * loc + oc + cls) + 0.5f * noobjf * no;
    }

    // wave64 reduce
    #pragma unroll
    for (int off = 32; off > 0; off >>= 1)
        part += __shfl_down(part, off, 64);

    __shared__ float ws[4];
    int lane = threadIdx.x & 63;
    int wid  = threadIdx.x >> 6;
    if (lane == 0) ws[wid] = part;
    __syncthreads();
    if (threadIdx.x == 0) {
        float s = ws[0] + ws[1] + ws[2] + ws[3];
        atomicAdd(out, s * invN);
    }
}

extern "C" void kernel_launch(void* const* d_in, const int* in_sizes, int n_in,
                              void* d_out, int out_size, void* d_ws, size_t ws_size,
                              hipStream_t stream) {
    const float* pred = (const float*)d_in[0];
    const float* tgt  = (const float*)d_in[1];
    float* out = (float*)d_out;

    const int M = in_sizes[1] / TSTRIDE;   // 8192*49 = 401408

    hipMemsetAsync(out, 0, sizeof(float), stream);

    int threads = 256;
    int blocks  = (M + threads - 1) / threads;
    yolo_loss_kernel<<<blocks, threads, 0, stream>>>(
        pred, tgt, out, M, 1.0f / (float)NBATCH);
}

// Round 2
// 38.730 us; speedup vs baseline: 1.0972x; 1.0972x over previous
//
#include <hip/hip_runtime.h>

// YOLO loss: S=7, B=2, C=20, LAMBDA_COORD=5, LAMBDA_NOOBJ=0.5, N=8192.
// pred: (8192, 49*30) f32, target: (8192, 49*25) f32, out: scalar f32.
// M = 8192*49 = 401408 cells, exactly divisible by 256.
// Block of 256 threads stages 256 cells into LDS with coalesced float4
// loads, then each thread computes one cell's loss term. Streaming
// reduction -> one atomicAdd per block.

#define NBATCH  8192
#define PSTRIDE 30         // 5*B + C
#define TSTRIDE 25         // 5 + C
#define TPB     256

__global__ __launch_bounds__(TPB) void yolo_loss_kernel(
    const float* __restrict__ pred,
    const float* __restrict__ tgt,
    float* __restrict__ out, float invN)
{
    __shared__ float sp[TPB * PSTRIDE];   // 7680 f = 30720 B
    __shared__ float st[TPB * TSTRIDE];   // 6400 f = 25600 B

    const int tid = threadIdx.x;
    const size_t c0 = (size_t)blockIdx.x * TPB;

    // ---- stage pred chunk: 1920 float4, fully coalesced & aligned ----
    const float4* gp = (const float4*)(pred + c0 * PSTRIDE);
    float4* lp = (float4*)sp;
    #pragma unroll
    for (int k = 0; k < 7; ++k)
        lp[tid + k * TPB] = gp[tid + k * TPB];
    if (tid < 128)                        // 1920 - 7*256
        lp[tid + 7 * TPB] = gp[tid + 7 * TPB];

    // ---- stage target chunk: 1600 float4 ----
    const float4* gt = (const float4*)(tgt + c0 * TSTRIDE);
    float4* lt = (float4*)st;
    #pragma unroll
    for (int k = 0; k < 6; ++k)
        lt[tid + k * TPB] = gt[tid + k * TPB];
    if (tid < 64)                         // 1600 - 6*256
        lt[tid + 6 * TPB] = gt[tid + 6 * TPB];

    __syncthreads();

    // ---- per-cell compute from LDS ----
    const float* p = sp + tid * PSTRIDE;
    const float* t = st + tid * TSTRIDE;

    int cell = (int)((c0 + tid) % 49);
    float gy = (float)(cell / 7);
    float gx = (float)(cell % 7);
    const float invS = 1.0f / 7.0f;

    float t0 = t[0], tx = t[1], ty = t[2], tw = t[3], th = t[4];
    float objf   = (t0 == 1.0f) ? 1.0f : 0.0f;
    float noobjf = (t0 == 0.0f) ? 1.0f : 0.0f;

    float tcx = (gx + tx) * invS, tcy = (gy + ty) * invS;
    float tx1 = tcx - tw * 0.5f, ty1 = tcy - th * 0.5f;
    float tx2 = tcx + tw * 0.5f, ty2 = tcy + th * 0.5f;
    float area_t = (tx2 - tx1) * (ty2 - ty1);

    float conf[2], bx[2], by[2], bw[2], bh[2], iou[2];
    #pragma unroll
    for (int b = 0; b < 2; ++b) {
        conf[b] = p[b * 5 + 0];
        bx[b]   = p[b * 5 + 1];
        by[b]   = p[b * 5 + 2];
        bw[b]   = p[b * 5 + 3];
        bh[b]   = p[b * 5 + 4];
        float ax = fabsf(bx[b]), ay = fabsf(by[b]);
        float aw = fabsf(bw[b]), ah = fabsf(bh[b]);
        float cx = (gx + ax) * invS, cy = (gy + ay) * invS;
        float x1 = cx - aw * 0.5f, y1 = cy - ah * 0.5f;
        float x2 = cx + aw * 0.5f, y2 = cy + ah * 0.5f;
        float ltx = fmaxf(x1, tx1), lty = fmaxf(y1, ty1);
        float rbx = fminf(x2, tx2), rby = fminf(y2, ty2);
        float wx = fmaxf(rbx - ltx, 0.0f);
        float wy = fmaxf(rby - lty, 0.0f);
        float inter = wx * wy;
        float area_p = (x2 - x1) * (y2 - y1);
        iou[b] = inter / (area_p + area_t - inter);
    }

    int best = (iou[1] > iou[0]) ? 1 : 0;       // first index wins ties
    float miou = fmaxf(iou[0], iou[1]);

    float rc = conf[best];
    float rx = bx[best], ry = by[best], rw = bw[best], rh = bh[best];

    float dx = rx - tx, dy = ry - ty;
    float sw = sqrtf(fabsf(rw)) - sqrtf(fabsf(tw));
    float sh = sqrtf(fabsf(rh)) - sqrtf(fabsf(th));
    float loc = dx * dx + dy * dy + sw * sw + sh * sh;

    float oc = rc - miou;
    oc = oc * oc;

    float no = conf[0] * conf[0] + conf[1] * conf[1];

    float cls = 0.0f;
    #pragma unroll
    for (int k = 0; k < 20; ++k) {
        float d = p[10 + k] - t[5 + k];
        cls += d * d;
    }

    float part = objf * (5.0f * loc + oc + cls) + 0.5f * noobjf * no;

    // ---- wave64 reduce, then cross-wave via LDS, one atomic/block ----
    #pragma unroll
    for (int off = 32; off > 0; off >>= 1)
        part += __shfl_down(part, off, 64);

    __shared__ float ws[4];
    int lane = tid & 63;
    int wid  = tid >> 6;
    if (lane == 0) ws[wid] = part;
    __syncthreads();
    if (tid == 0) {
        float s = ws[0] + ws[1] + ws[2] + ws[3];
        atomicAdd(out, s * invN);
    }
}

extern "C" void kernel_launch(void* const* d_in, const int* in_sizes, int n_in,
                              void* d_out, int out_size, void* d_ws, size_t ws_size,
                              hipStream_t stream) {
    const float* pred = (const float*)d_in[0];
    const float* tgt  = (const float*)d_in[1];
    float* out = (float*)d_out;

    const int M = in_sizes[1] / TSTRIDE;   // 401408
    const int blocks = M / TPB;            // 1568 (exact)

    hipMemsetAsync(out, 0, sizeof(float), stream);

    yolo_loss_kernel<<<blocks, TPB, 0, stream>>>(
        pred, tgt, out, 1.0f / (float)NBATCH);
}

// Round 3
// 25.197 us; speedup vs baseline: 1.6865x; 1.5371x over previous
//
#include <hip/hip_runtime.h>

// YOLO loss: S=7, B=2, C=20, LAMBDA_COORD=5, LAMBDA_NOOBJ=0.5, N=8192.
// pred: (8192, 49*30) f32, target: (8192, 49*25) f32, out: scalar f32.
// M = 8192*49 = 401408 cells = 1568 chunks of 256.
// Kernel 1: block stages its 256-cell chunk into LDS (coalesced float4),
//           computes per-cell loss, reduces, plain-stores partial to d_ws.
// Kernel 2: one block sums the 1568 partials, stores out[0] = sum/N.
// No memset, no atomics -> no same-address contention, no extra dispatch.

#define NBATCH  8192
#define PSTRIDE 30         // 5*B + C
#define TSTRIDE 25         // 5 + C
#define TPB     256
#define NCHUNKS 1568       // M / TPB

__global__ __launch_bounds__(TPB) void yolo_partial_kernel(
    const float* __restrict__ pred,
    const float* __restrict__ tgt,
    float* __restrict__ partials)
{
    __shared__ float sp[TPB * PSTRIDE];   // 30720 B
    __shared__ float st[TPB * TSTRIDE];   // 25600 B

    const int tid = threadIdx.x;
    const size_t c0 = (size_t)blockIdx.x * TPB;

    // ---- stage pred chunk: 1920 float4, coalesced & 16B-aligned ----
    const float4* gp = (const float4*)(pred + c0 * PSTRIDE);
    float4* lp = (float4*)sp;
    #pragma unroll
    for (int k = 0; k < 7; ++k)
        lp[tid + k * TPB] = gp[tid + k * TPB];
    if (tid < 128)
        lp[tid + 7 * TPB] = gp[tid + 7 * TPB];

    // ---- stage target chunk: 1600 float4 ----
    const float4* gt = (const float4*)(tgt + c0 * TSTRIDE);
    float4* lt = (float4*)st;
    #pragma unroll
    for (int k = 0; k < 6; ++k)
        lt[tid + k * TPB] = gt[tid + k * TPB];
    if (tid < 64)
        lt[tid + 6 * TPB] = gt[tid + 6 * TPB];

    __syncthreads();

    // ---- per-cell compute from LDS ----
    const float* p = sp + tid * PSTRIDE;
    const float* t = st + tid * TSTRIDE;

    int cell = (int)((c0 + tid) % 49);
    float gy = (float)(cell / 7);
    float gx = (float)(cell % 7);
    const float invS = 1.0f / 7.0f;

    float t0 = t[0], tx = t[1], ty = t[2], tw = t[3], th = t[4];
    float objf   = (t0 == 1.0f) ? 1.0f : 0.0f;
    float noobjf = (t0 == 0.0f) ? 1.0f : 0.0f;

    float tcx = (gx + tx) * invS, tcy = (gy + ty) * invS;
    float tx1 = tcx - tw * 0.5f, ty1 = tcy - th * 0.5f;
    float tx2 = tcx + tw * 0.5f, ty2 = tcy + th * 0.5f;
    float area_t = (tx2 - tx1) * (ty2 - ty1);

    float conf[2], bx[2], by[2], bw[2], bh[2], iou[2];
    #pragma unroll
    for (int b = 0; b < 2; ++b) {
        conf[b] = p[b * 5 + 0];
        bx[b]   = p[b * 5 + 1];
        by[b]   = p[b * 5 + 2];
        bw[b]   = p[b * 5 + 3];
        bh[b]   = p[b * 5 + 4];
        float ax = fabsf(bx[b]), ay = fabsf(by[b]);
        float aw = fabsf(bw[b]), ah = fabsf(bh[b]);
        float cx = (gx + ax) * invS, cy = (gy + ay) * invS;
        float x1 = cx - aw * 0.5f, y1 = cy - ah * 0.5f;
        float x2 = cx + aw * 0.5f, y2 = cy + ah * 0.5f;
        float ltx = fmaxf(x1, tx1), lty = fmaxf(y1, ty1);
        float rbx = fminf(x2, tx2), rby = fminf(y2, ty2);
        float wx = fmaxf(rbx - ltx, 0.0f);
        float wy = fmaxf(rby - lty, 0.0f);
        float inter = wx * wy;
        float area_p = (x2 - x1) * (y2 - y1);
        iou[b] = inter / (area_p + area_t - inter);
    }

    int best = (iou[1] > iou[0]) ? 1 : 0;       // first index wins ties
    float miou = fmaxf(iou[0], iou[1]);

    float rc = conf[best];
    float rx = bx[best], ry = by[best], rw = bw[best], rh = bh[best];

    float dx = rx - tx, dy = ry - ty;
    float sw = sqrtf(fabsf(rw)) - sqrtf(fabsf(tw));
    float sh = sqrtf(fabsf(rh)) - sqrtf(fabsf(th));
    float loc = dx * dx + dy * dy + sw * sw + sh * sh;

    float oc = rc - miou;
    oc = oc * oc;

    float no = conf[0] * conf[0] + conf[1] * conf[1];

    float cls = 0.0f;
    #pragma unroll
    for (int k = 0; k < 20; ++k) {
        float d = p[10 + k] - t[5 + k];
        cls += d * d;
    }

    float part = objf * (5.0f * loc + oc + cls) + 0.5f * noobjf * no;

    // ---- wave64 reduce, cross-wave via LDS, one plain store/block ----
    #pragma unroll
    for (int off = 32; off > 0; off >>= 1)
        part += __shfl_down(part, off, 64);

    __shared__ float ws[4];
    int lane = tid & 63;
    int wid  = tid >> 6;
    if (lane == 0) ws[wid] = part;
    __syncthreads();
    if (tid == 0)
        partials[blockIdx.x] = ws[0] + ws[1] + ws[2] + ws[3];
}

__global__ __launch_bounds__(TPB) void yolo_final_kernel(
    const float* __restrict__ partials,
    float* __restrict__ out, float invN)
{
    const int tid = threadIdx.x;
    float s = 0.0f;
    for (int i = tid; i < NCHUNKS; i += TPB)
        s += partials[i];

    #pragma unroll
    for (int off = 32; off > 0; off >>= 1)
        s += __shfl_down(s, off, 64);

    __shared__ float ws[4];
    int lane = tid & 63;
    int wid  = tid >> 6;
    if (lane == 0) ws[wid] = s;
    __syncthreads();
    if (tid == 0)
        out[0] = (ws[0] + ws[1] + ws[2] + ws[3]) * invN;
}

extern "C" void kernel_launch(void* const* d_in, const int* in_sizes, int n_in,
                              void* d_out, int out_size, void* d_ws, size_t ws_size,
                              hipStream_t stream) {
    const float* pred = (const float*)d_in[0];
    const float* tgt  = (const float*)d_in[1];
    float* out = (float*)d_out;
    float* partials = (float*)d_ws;        // 1568 floats, overwritten fully

    yolo_partial_kernel<<<NCHUNKS, TPB, 0, stream>>>(pred, tgt, partials);
    yolo_final_kernel<<<1, TPB, 0, stream>>>(partials, out, 1.0f / (float)NBATCH);
}